// Round 6
// baseline (194.669 us; speedup 1.0000x reference)
//
#include <hip/hip_runtime.h>
#include <math.h>

#define B 32
#define C 256
#define M 64
#define N 4096  // H*W

typedef __attribute__((ext_vector_type(8))) short s16x8;
typedef __attribute__((ext_vector_type(8))) __bf16 bf16x8;
typedef __attribute__((ext_vector_type(4))) float f32x4;
typedef __attribute__((ext_vector_type(4))) unsigned short u16x4;
typedef __attribute__((ext_vector_type(8))) unsigned short u16x8;

static constexpr float EPS = 1e-12f;

__device__ __forceinline__ unsigned short f2bf(float f) {
    unsigned u = __float_as_uint(f);
    u += 0x7FFFu + ((u >> 16) & 1u);  // RNE
    return (unsigned short)(u >> 16);
}
__device__ __forceinline__ float bf2f(unsigned short h) {
    return __uint_as_float((unsigned)h << 16);
}
__device__ __forceinline__ f32x4 MFMA(s16x8 a, s16x8 b, f32x4 c) {
    return __builtin_amdgcn_mfma_f32_16x16x32_bf16(
        __builtin_bit_cast(bf16x8, a), __builtin_bit_cast(bf16x8, b), c, 0, 0, 0);
}
__device__ __forceinline__ s16x8 cvt8(const f32x4 a, const f32x4 b) {
    bf16x8 h;
    h[0] = (__bf16)a[0]; h[1] = (__bf16)a[1]; h[2] = (__bf16)a[2]; h[3] = (__bf16)a[3];
    h[4] = (__bf16)b[0]; h[5] = (__bf16)b[1]; h[6] = (__bf16)b[2]; h[7] = (__bf16)b[3];
    return __builtin_bit_cast(s16x8, h);
}
// LDS column swizzle for the [n][c] bf16 tile (halfword units, flips bits 3-5 of c)
__device__ __forceinline__ int swz(int n) {
    return (((n >> 2) & 3) | ((n & 1) << 2)) << 3;
}

__global__ __launch_bounds__(256) void kW_convert(const float* __restrict__ Wf,
                                                  unsigned short* __restrict__ Wb) {
    const int i = blockIdx.x * 256 + threadIdx.x;  // M*C = 16384
    Wb[i] = f2bf(Wf[i]);
}

// ---------------------------------------------------------------------------
// K01: fused convert + transpose + logits. Phase A: 4c x 4n register blocks,
// ds_write_b64 staging (16 LDS writes/thread).
// ---------------------------------------------------------------------------
__global__ __launch_bounds__(256) void k01(const float* __restrict__ x,
                                           const unsigned short* __restrict__ Wb,
                                           unsigned short* __restrict__ xbt,
                                           unsigned short* __restrict__ Sb,
                                           float* __restrict__ xsq) {
    const int nb = blockIdx.x, b = blockIdx.y;
    const int t = threadIdx.x;
    __shared__ unsigned short tsT[64 * 256];
    __shared__ float xred[16][68];
    // ---- phase A ----
    const int nq = t & 15, cq = t >> 4;
    float part[4] = {0.f, 0.f, 0.f, 0.f};
    const float* xrow = x + (size_t)b * C * N + (size_t)nb * 64 + 4 * nq;
#pragma unroll
    for (int step = 0; step < 4; ++step) {
        const int c0 = cq * 4 + step * 64;
        f32x4 q[4];
#pragma unroll
        for (int i = 0; i < 4; ++i) q[i] = *(const f32x4*)(xrow + (size_t)(c0 + i) * N);
#pragma unroll
        for (int k = 0; k < 4; ++k) {
            const int n = 4 * nq + k;
            u16x4 h;
#pragma unroll
            for (int i = 0; i < 4; ++i) {
                part[k] += q[i][k] * q[i][k];
                h[i] = f2bf(q[i][k]);
            }
            *(u16x4*)(&tsT[n * 256 + (c0 ^ swz(n))]) = h;
        }
    }
#pragma unroll
    for (int k = 0; k < 4; ++k) xred[cq][4 * nq + k] = part[k];
    __syncthreads();
    if (t < 64) {
        float s = 0.f;
#pragma unroll
        for (int j = 0; j < 16; ++j) s += xred[j][t];
        xsq[(size_t)b * N + nb * 64 + t] = s;
    }
    // ---- phase B1: xbt coalesced write ----
    {
        const int l = t & 31, nh = t >> 5;
#pragma unroll
        for (int j = 0; j < 8; ++j) {
            const int n = nh + 8 * j;
            const int c0 = l * 8;
            const u16x8 v = *(const u16x8*)(&tsT[n * 256 + (c0 ^ swz(n))]);
            *(u16x8*)(xbt + ((size_t)b * N + nb * 64 + n) * C + c0) = v;
        }
    }
    // ---- phase B2: logits MFMA ----
    const int wv = t >> 6, lane = t & 63, li = lane & 15, lk = lane >> 4;
    const f32x4 zv = {0.f, 0.f, 0.f, 0.f};
    f32x4 acc[4] = {zv, zv, zv, zv};
    const unsigned short* br = Wb + (size_t)(wv * 16 + li) * C + lk * 8;
#pragma unroll
    for (int c0 = 0; c0 < C; c0 += 32) {
        const s16x8 bfrag = *(const s16x8*)(br + c0);
#pragma unroll
        for (int s = 0; s < 4; ++s) {
            const int n = s * 16 + li;
            const s16x8 a = *(const s16x8*)(&tsT[n * 256 + ((lk * 8 + c0) ^ swz(n))]);
            acc[s] = MFMA(a, bfrag, acc[s]);
        }
    }
    unsigned short* Srow = Sb + ((size_t)b * M + wv * 16 + li) * N + nb * 64;
#pragma unroll
    for (int s = 0; s < 4; ++s) {
        u16x4 h;
#pragma unroll
        for (int r = 0; r < 4; ++r) h[r] = f2bf(acc[s][r]);
        *(u16x4*)(Srow + s * 16 + lk * 4) = h;
    }
}

// ---------------------------------------------------------------------------
// K2: softmax over n per (b,m); bf16 in -> bf16 out. (verified)
// ---------------------------------------------------------------------------
__global__ __launch_bounds__(256) void k2_softmax_n(const unsigned short* __restrict__ Sb,
                                                    unsigned short* __restrict__ Pb) {
    const int m = blockIdx.x, b = blockIdx.y;
    const unsigned short* col = Sb + ((size_t)b * M + m) * N;
    unsigned short* po = Pb + ((size_t)b * M + m) * N;
    const int t = threadIdx.x;
    float v[16];
    const u16x8 h0 = *(const u16x8*)(col + t * 16);
    const u16x8 h1 = *(const u16x8*)(col + t * 16 + 8);
#pragma unroll
    for (int i = 0; i < 8; ++i) v[i] = bf2f(h0[i]);
#pragma unroll
    for (int i = 0; i < 8; ++i) v[8 + i] = bf2f(h1[i]);
    float mx = -INFINITY;
#pragma unroll
    for (int i = 0; i < 16; ++i) mx = fmaxf(mx, v[i]);
#pragma unroll
    for (int off = 32; off >= 1; off >>= 1) mx = fmaxf(mx, __shfl_xor(mx, off));
    __shared__ float redm[4], reds[4];
    const int wave = t >> 6, lane = t & 63;
    if (lane == 0) redm[wave] = mx;
    __syncthreads();
    mx = fmaxf(fmaxf(redm[0], redm[1]), fmaxf(redm[2], redm[3]));
    float s = 0.f;
#pragma unroll
    for (int i = 0; i < 16; ++i) {
        v[i] = __expf(v[i] - mx);
        s += v[i];
    }
#pragma unroll
    for (int off = 32; off >= 1; off >>= 1) s += __shfl_xor(s, off);
    if (lane == 0) reds[wave] = s;
    __syncthreads();
    s = reds[0] + reds[1] + reds[2] + reds[3];
    const float inv = 1.f / s;
    u16x8 o0, o1;
#pragma unroll
    for (int i = 0; i < 8; ++i) o0[i] = f2bf(v[i] * inv);
#pragma unroll
    for (int i = 0; i < 8; ++i) o1[i] = f2bf(v[8 + i] * inv);
    *(u16x8*)(po + t * 16) = o0;
    *(u16x8*)(po + t * 16 + 8) = o1;
}

// ---------------------------------------------------------------------------
// K3: proto partials parts[b][ck][m][c] over 512-n chunks. (verified)
// ---------------------------------------------------------------------------
__global__ __launch_bounds__(256) void k3_mfma(const float* __restrict__ x,
                                               const unsigned short* __restrict__ Pb,
                                               float* __restrict__ parts) {
    const int ck = blockIdx.x, b = blockIdx.y;
    const int wv = threadIdx.x >> 6, lane = threadIdx.x & 63;
    const int li = lane & 15, lk = lane >> 4;
    const int c0w = wv * 64;
    const int nb = ck * 512;
    const f32x4 zv = {0.f, 0.f, 0.f, 0.f};
    f32x4 acc[4][4];
#pragma unroll
    for (int s = 0; s < 4; ++s)
#pragma unroll
        for (int u = 0; u < 4; ++u) acc[s][u] = zv;
    const float* ar = x + ((size_t)b * C + c0w + li) * N + nb + lk * 8;
    const unsigned short* br = Pb + ((size_t)b * M + li) * N + nb + lk * 8;
#pragma unroll 4
    for (int n0 = 0; n0 < 512; n0 += 32) {
        s16x8 af[4], bf_[4];
#pragma unroll
        for (int s = 0; s < 4; ++s) {
            const float* p = ar + (size_t)(s * 16) * N + n0;
            af[s] = cvt8(*(const f32x4*)p, *(const f32x4*)(p + 4));
        }
#pragma unroll
        for (int u = 0; u < 4; ++u) bf_[u] = *(const s16x8*)(br + (size_t)(u * 16) * N + n0);
#pragma unroll
        for (int s = 0; s < 4; ++s)
#pragma unroll
            for (int u = 0; u < 4; ++u) acc[s][u] = MFMA(af[s], bf_[u], acc[s][u]);
    }
    float* pp = parts + ((size_t)b * 8 + ck) * M * C;
#pragma unroll
    for (int s = 0; s < 4; ++s)
#pragma unroll
        for (int u = 0; u < 4; ++u)
            *(f32x4*)(pp + (size_t)(u * 16 + li) * C + c0w + s * 16 + lk * 4) = acc[s][u];
}

// ---------------------------------------------------------------------------
// K3b: reduce 8 chunks -> l2norm -> proto_bf [m][c], protoT_bf [c][m], p2.
// ---------------------------------------------------------------------------
__global__ __launch_bounds__(256) void k3b_reduce(const float* __restrict__ parts,
                                                  unsigned short* __restrict__ proto_bf,
                                                  unsigned short* __restrict__ protoT_bf,
                                                  float* __restrict__ p2) {
    const int mb = blockIdx.x, b = blockIdx.y;
    const int t = threadIdx.x;
    const int ml = t >> 5, cl = t & 31;
    const int m = mb * 8 + ml;
    const int c0 = cl * 8;
    float v[8] = {0.f, 0.f, 0.f, 0.f, 0.f, 0.f, 0.f, 0.f};
    const float* pbase = parts + (size_t)b * 8 * M * C + (size_t)m * C + c0;
#pragma unroll
    for (int ck = 0; ck < 8; ++ck) {
        const f32x4 q0 = *(const f32x4*)(pbase + (size_t)ck * M * C);
        const f32x4 q1 = *(const f32x4*)(pbase + (size_t)ck * M * C + 4);
#pragma unroll
        for (int j = 0; j < 4; ++j) { v[j] += q0[j]; v[4 + j] += q1[j]; }
    }
    float sq = 0.f;
#pragma unroll
    for (int j = 0; j < 8; ++j) sq += v[j] * v[j];
#pragma unroll
    for (int off = 16; off >= 1; off >>= 1) sq += __shfl_xor(sq, off);
    const float denom = fmaxf(sqrtf(sq), EPS);
    const float scale = 1.f / denom;
    if (cl == 0) p2[b * M + m] = sq / (denom * denom);
    u16x8 h;
#pragma unroll
    for (int j = 0; j < 8; ++j) h[j] = f2bf(v[j] * scale);
    *(u16x8*)(proto_bf + ((size_t)b * M + m) * C + c0) = h;
#pragma unroll
    for (int j = 0; j < 8; ++j)
        protoT_bf[((size_t)b * C + c0 + j) * M + m] = h[j];
}

// ---------------------------------------------------------------------------
// K4F: fused score + softmax-m + compact partials + PV + c-norm + store.
// 512 threads. Phase1: wave w owns 32 n (m all 64). P -> swizzled LDS.
// Phase2: wave (nq=w&3, ch=w>>2) owns 64n x 128c; c-norm via LDS; f32x4 stores.
// Reads ONLY ws-resident buffers -> no race with its own out writes.
// ---------------------------------------------------------------------------
__global__ __launch_bounds__(512) void k4f(const unsigned short* __restrict__ proto_bf,
                                           const unsigned short* __restrict__ protoT_bf,
                                           const unsigned short* __restrict__ xbt,
                                           const float* __restrict__ p2,
                                           const float* __restrict__ xsq,
                                           float* __restrict__ out,
                                           float* __restrict__ cparts) {
    const int b = blockIdx.y;
    const int t = threadIdx.x;
    const int w = t >> 6, lane = t & 63, li = lane & 15, lk = lane >> 4;
    const int nblk = blockIdx.x * 256;
    __shared__ unsigned short p_lds[256 * 64];  // [n_local][m], byte ^ ((n&7)<<4)
    __shared__ float red2[2][256];
    __shared__ float red8[8];
    const f32x4 zv = {0.f, 0.f, 0.f, 0.f};
    // ---- phase 1: QK^T ----
    f32x4 acc[4][2];
#pragma unroll
    for (int s = 0; s < 4; ++s)
#pragma unroll
        for (int u = 0; u < 2; ++u) acc[s][u] = zv;
    const unsigned short* ar = proto_bf + (size_t)b * M * C + (size_t)li * C + lk * 8;
    const unsigned short* br = xbt + ((size_t)b * N + nblk + w * 32 + li) * C + lk * 8;
#pragma unroll
    for (int c0 = 0; c0 < C; c0 += 32) {
        s16x8 af[4], bf_[2];
#pragma unroll
        for (int s = 0; s < 4; ++s) af[s] = *(const s16x8*)(ar + (size_t)(s * 16) * C + c0);
#pragma unroll
        for (int u = 0; u < 2; ++u) bf_[u] = *(const s16x8*)(br + (size_t)(u * 16) * C + c0);
#pragma unroll
        for (int s = 0; s < 4; ++s)
#pragma unroll
            for (int u = 0; u < 2; ++u) acc[s][u] = MFMA(af[s], bf_[u], acc[s][u]);
    }
    // softmax over m per pixel (m spread over s,r in-lane and lk across lanes)
    float csum = 0.f;
#pragma unroll
    for (int u = 0; u < 2; ++u) {
        const int n = nblk + w * 32 + u * 16 + li;
        const int nl = w * 32 + u * 16 + li;
        float vmax = -INFINITY;
#pragma unroll
        for (int s = 0; s < 4; ++s)
#pragma unroll
            for (int r = 0; r < 4; ++r) vmax = fmaxf(vmax, acc[s][u][r]);
        vmax = fmaxf(vmax, __shfl_xor(vmax, 16));
        vmax = fmaxf(vmax, __shfl_xor(vmax, 32));
        int t1 = 1 << 30;
#pragma unroll
        for (int s = 0; s < 4; ++s)
#pragma unroll
            for (int r = 0; r < 4; ++r)
                if (acc[s][u][r] == vmax) t1 = min(t1, s * 16 + lk * 4 + r);
        t1 = min(t1, __shfl_xor(t1, 16));
        t1 = min(t1, __shfl_xor(t1, 32));
        float es = 0.f;
#pragma unroll
        for (int s = 0; s < 4; ++s)
#pragma unroll
            for (int r = 0; r < 4; ++r) {
                const float e = __expf(acc[s][u][r] - vmax);
                acc[s][u][r] = e;
                es += e;
            }
        es += __shfl_xor(es, 16);
        es += __shfl_xor(es, 32);
        const float inv = 1.f / es;
#pragma unroll
        for (int s = 0; s < 4; ++s) {
            u16x4 h;
#pragma unroll
            for (int r = 0; r < 4; ++r) h[r] = f2bf(acc[s][u][r] * inv);
            const unsigned off =
                (unsigned)((nl * 128 + ((s * 16 + lk * 4) << 1)) ^ ((nl & 7) << 4));
            *(u16x4*)((char*)p_lds + off) = h;
        }
        if (lk == 0) csum += xsq[(size_t)b * N + n] - 2.f * vmax + p2[b * M + t1];
    }
#pragma unroll
    for (int off = 32; off >= 1; off >>= 1) csum += __shfl_xor(csum, off);
    if (lane == 0) red8[w] = csum;
    __syncthreads();
    if (t == 0) {
        float cs = 0.f;
#pragma unroll
        for (int j = 0; j < 8; ++j) cs += red8[j];
        cparts[b * 16 + blockIdx.x] = cs;
    }
    // ---- phase 2: PV ----
    const int nq = w & 3, ch = w >> 2;
    f32x4 a2[4][8];
#pragma unroll
    for (int s = 0; s < 4; ++s)
#pragma unroll
        for (int u = 0; u < 8; ++u) a2[s][u] = zv;
    const unsigned short* br2 =
        protoT_bf + ((size_t)b * C + ch * 128 + li) * M + lk * 8;
#pragma unroll
    for (int m0 = 0; m0 < M; m0 += 32) {
        s16x8 af2[4], bf2[8];
#pragma unroll
        for (int s = 0; s < 4; ++s) {
            const int nl = nq * 64 + s * 16 + li;
            const unsigned off =
                (unsigned)((nl * 128 + ((m0 + lk * 8) << 1)) ^ ((nl & 7) << 4));
            af2[s] = *(const s16x8*)((const char*)p_lds + off);
        }
#pragma unroll
        for (int u = 0; u < 8; ++u)
            bf2[u] = *(const s16x8*)(br2 + (size_t)(u * 16) * M + m0);
#pragma unroll
        for (int s = 0; s < 4; ++s)
#pragma unroll
            for (int u = 0; u < 8; ++u) a2[s][u] = MFMA(af2[s], bf2[u], a2[s][u]);
    }
    // per-n ssq over this wave's 128 c, then cross-ch via LDS
    float ssq[4][4];
#pragma unroll
    for (int s = 0; s < 4; ++s)
#pragma unroll
        for (int r = 0; r < 4; ++r) {
            float sum = 0.f;
#pragma unroll
            for (int u = 0; u < 8; ++u) sum += a2[s][u][r] * a2[s][u][r];
#pragma unroll
            for (int off = 8; off >= 1; off >>= 1) sum += __shfl_xor(sum, off);
            ssq[s][r] = sum;
        }
    if (li == 0) {
#pragma unroll
        for (int s = 0; s < 4; ++s)
#pragma unroll
            for (int r = 0; r < 4; ++r)
                red2[ch][nq * 64 + s * 16 + lk * 4 + r] = ssq[s][r];
    }
    __syncthreads();
    float scl[4][4];
#pragma unroll
    for (int s = 0; s < 4; ++s)
#pragma unroll
        for (int r = 0; r < 4; ++r) {
            const int nl = nq * 64 + s * 16 + lk * 4 + r;
            scl[s][r] = 1.f / fmaxf(sqrtf(red2[0][nl] + red2[1][nl]), EPS);
        }
    float* ob = out + (size_t)b * C * N;
#pragma unroll
    for (int s = 0; s < 4; ++s)
#pragma unroll
        for (int u = 0; u < 8; ++u) {
            const int c = ch * 128 + u * 16 + li;
            f32x4 q;
#pragma unroll
            for (int r = 0; r < 4; ++r) q[r] = a2[s][u][r] * scl[s][r];
            *(f32x4*)(ob + (size_t)c * N + nblk + nq * 64 + s * 16 + lk * 4) = q;
        }
}

// ---------------------------------------------------------------------------
// K4 (fallback): score + softmax-m + compact partials -> pnm global.
// ---------------------------------------------------------------------------
__global__ __launch_bounds__(256) void k4_score(const unsigned short* __restrict__ proto_bf,
                                                const unsigned short* __restrict__ xbt,
                                                const float* __restrict__ p2,
                                                const float* __restrict__ xsq,
                                                unsigned short* __restrict__ pnm,
                                                float* __restrict__ cparts) {
    const int b = blockIdx.y;
    const int wv = threadIdx.x >> 6, lane = threadIdx.x & 63;
    const int li = lane & 15, lk = lane >> 4;
    const int nbase = blockIdx.x * 256 + wv * 64;
    const f32x4 zv = {0.f, 0.f, 0.f, 0.f};
    f32x4 acc[4][4];
#pragma unroll
    for (int s = 0; s < 4; ++s)
#pragma unroll
        for (int u = 0; u < 4; ++u) acc[s][u] = zv;
    const unsigned short* ar = proto_bf + ((size_t)b * M + li) * C + lk * 8;
    const unsigned short* br = xbt + ((size_t)b * N + nbase + li) * C + lk * 8;
#pragma unroll
    for (int c0 = 0; c0 < C; c0 += 32) {
        s16x8 af[4], bf_[4];
#pragma unroll
        for (int s = 0; s < 4; ++s) af[s] = *(const s16x8*)(ar + (size_t)(s * 16) * C + c0);
#pragma unroll
        for (int u = 0; u < 4; ++u) bf_[u] = *(const s16x8*)(br + (size_t)(u * 16) * C + c0);
#pragma unroll
        for (int s = 0; s < 4; ++s)
#pragma unroll
            for (int u = 0; u < 4; ++u) acc[s][u] = MFMA(af[s], bf_[u], acc[s][u]);
    }
    float csum = 0.f;
#pragma unroll
    for (int u = 0; u < 4; ++u) {
        const int n = nbase + u * 16 + li;
        float vmax = -INFINITY;
#pragma unroll
        for (int s = 0; s < 4; ++s)
#pragma unroll
            for (int r = 0; r < 4; ++r) vmax = fmaxf(vmax, acc[s][u][r]);
        vmax = fmaxf(vmax, __shfl_xor(vmax, 16));
        vmax = fmaxf(vmax, __shfl_xor(vmax, 32));
        int t1 = 1 << 30;
#pragma unroll
        for (int s = 0; s < 4; ++s)
#pragma unroll
            for (int r = 0; r < 4; ++r)
                if (acc[s][u][r] == vmax) t1 = min(t1, s * 16 + lk * 4 + r);
        t1 = min(t1, __shfl_xor(t1, 16));
        t1 = min(t1, __shfl_xor(t1, 32));
        float es = 0.f;
#pragma unroll
        for (int s = 0; s < 4; ++s)
#pragma unroll
            for (int r = 0; r < 4; ++r) {
                const float e = __expf(acc[s][u][r] - vmax);
                acc[s][u][r] = e;
                es += e;
            }
        es += __shfl_xor(es, 16);
        es += __shfl_xor(es, 32);
        const float inv = 1.f / es;
        unsigned short* prow = pnm + ((size_t)b * N + n) * M;
#pragma unroll
        for (int s = 0; s < 4; ++s) {
            u16x4 h;
#pragma unroll
            for (int r = 0; r < 4; ++r) h[r] = f2bf(acc[s][u][r] * inv);
            *(u16x4*)(prow + s * 16 + lk * 4) = h;
        }
        if (lk == 0) csum += xsq[(size_t)b * N + n] - 2.f * vmax + p2[b * M + t1];
    }
#pragma unroll
    for (int off = 32; off >= 1; off >>= 1) csum += __shfl_xor(csum, off);
    __shared__ float red[4];
    if (lane == 0) red[wv] = csum;
    __syncthreads();
    if (threadIdx.x == 0)
        cparts[b * 16 + blockIdx.x] = red[0] + red[1] + red[2] + red[3];
}

// ---------------------------------------------------------------------------
// K4b (fallback): out = l2norm_c(sum_m p[n][m]*protoT[c][m]).
// ---------------------------------------------------------------------------
__global__ __launch_bounds__(256) void k4b_mfma(const unsigned short* __restrict__ pnm,
                                                const unsigned short* __restrict__ protoT_bf,
                                                float* __restrict__ out) {
    const int b = blockIdx.y;
    const int wv = threadIdx.x >> 6, lane = threadIdx.x & 63;
    const int li = lane & 15, lk = lane >> 4;
    const int n0 = blockIdx.x * 64;
    const int cb = wv * 64;
    const f32x4 zv = {0.f, 0.f, 0.f, 0.f};
    f32x4 acc[4][4];
#pragma unroll
    for (int s = 0; s < 4; ++s)
#pragma unroll
        for (int u = 0; u < 4; ++u) acc[s][u] = zv;
    const unsigned short* ar = pnm + ((size_t)b * N + n0 + li) * M + lk * 8;
    const unsigned short* br = protoT_bf + ((size_t)b * C + cb + li) * M + lk * 8;
#pragma unroll
    for (int m0 = 0; m0 < M; m0 += 32) {
        s16x8 af[4], bf_[4];
#pragma unroll
        for (int s = 0; s < 4; ++s) af[s] = *(const s16x8*)(ar + (size_t)(s * 16) * M + m0);
#pragma unroll
        for (int u = 0; u < 4; ++u) bf_[u] = *(const s16x8*)(br + (size_t)(u * 16) * M + m0);
#pragma unroll
        for (int s = 0; s < 4; ++s)
#pragma unroll
            for (int u = 0; u < 4; ++u) acc[s][u] = MFMA(af[s], bf_[u], acc[s][u]);
    }
    __shared__ float ls[4][64];
    __shared__ float ls2[64];
    float psq[4][4];
#pragma unroll
    for (int s = 0; s < 4; ++s)
#pragma unroll
        for (int r = 0; r < 4; ++r) {
            float sum = 0.f;
#pragma unroll
            for (int u = 0; u < 4; ++u) sum += acc[s][u][r] * acc[s][u][r];
#pragma unroll
            for (int off = 8; off >= 1; off >>= 1) sum += __shfl_xor(sum, off);
            psq[s][r] = sum;
        }
    if (li == 0) {
#pragma unroll
        for (int s = 0; s < 4; ++s)
#pragma unroll
            for (int r = 0; r < 4; ++r) ls[wv][s * 16 + lk * 4 + r] = psq[s][r];
    }
    __syncthreads();
    if (threadIdx.x < 64) {
        const int tt = threadIdx.x;
        const float tot = ls[0][tt] + ls[1][tt] + ls[2][tt] + ls[3][tt];
        ls2[tt] = 1.f / fmaxf(sqrtf(tot), EPS);
    }
    __syncthreads();
    float scl[4][4];
#pragma unroll
    for (int s = 0; s < 4; ++s)
#pragma unroll
        for (int r = 0; r < 4; ++r) scl[s][r] = ls2[s * 16 + lk * 4 + r];
    float* ob = out + (size_t)b * C * N;
#pragma unroll
    for (int s = 0; s < 4; ++s)
#pragma unroll
        for (int u = 0; u < 4; ++u) {
            f32x4 q;
#pragma unroll
            for (int r = 0; r < 4; ++r) q[r] = acc[s][u][r] * scl[s][r];
            *(f32x4*)(ob + (size_t)(cb + u * 16 + li) * N + n0 + s * 16 + lk * 4) = q;
        }
}

// ---------------------------------------------------------------------------
// K5 / K6: losses. (verified)
// ---------------------------------------------------------------------------
__global__ __launch_bounds__(256) void k5_dis(const unsigned short* __restrict__ proto_bf,
                                              const float* __restrict__ p2,
                                              float* __restrict__ dparts) {
    const int q = blockIdx.x;
    const int b = blockIdx.y;
    const unsigned short* pr = proto_bf + (size_t)b * M * C;
    __shared__ float pl[M * C];
    for (int idx = threadIdx.x; idx < M * C; idx += 256) {
        int m = idx >> 8, c = idx & 255;
        pl[m * 256 + (c ^ (m & 31))] = bf2f(pr[idx]);
    }
    __syncthreads();
    float sum = 0.f;
    for (int k = 0; k < 2; ++k) {
        const int pair = q * 512 + k * 256 + threadIdx.x;
        const int i = pair >> 6, j = pair & 63;
        if (j > i) {
            float g = 0.f;
#pragma unroll 8
            for (int c = 0; c < C; ++c)
                g += pl[i * 256 + (c ^ (i & 31))] * pl[j * 256 + (c ^ (j & 31))];
            const float d = 1.f - (p2[b * M + i] + p2[b * M + j] - 2.f * g);
            sum += fmaxf(d, 0.f);
        }
    }
#pragma unroll
    for (int off = 32; off >= 1; off >>= 1) sum += __shfl_xor(sum, off);
    __shared__ float red[4];
    const int wave = threadIdx.x >> 6, lane = threadIdx.x & 63;
    if (lane == 0) red[wave] = sum;
    __syncthreads();
    if (threadIdx.x == 0) dparts[b * 8 + q] = red[0] + red[1] + red[2] + red[3];
}

__global__ __launch_bounds__(256) void k6_final(const float* __restrict__ cparts,
                                                const float* __restrict__ dparts,
                                                float* __restrict__ losses) {
    const int t = threadIdx.x;
    float cs = cparts[t] + cparts[t + 256];
    float ds = dparts[t];
#pragma unroll
    for (int off = 32; off >= 1; off >>= 1) {
        cs += __shfl_xor(cs, off);
        ds += __shfl_xor(ds, off);
    }
    __shared__ float rc[4], rd[4];
    const int wave = t >> 6, lane = t & 63;
    if (lane == 0) { rc[wave] = cs; rd[wave] = ds; }
    __syncthreads();
    if (t == 0) {
        const float ctot = rc[0] + rc[1] + rc[2] + rc[3];
        const float dtot = rd[0] + rd[1] + rd[2] + rd[3];
        losses[0] = ctot / ((float)B * (float)N * (float)C);
        losses[1] = dtot * (2.f / (float)(M * (M - 1))) / (float)B;
    }
}

extern "C" void kernel_launch(void* const* d_in, const int* in_sizes, int n_in,
                              void* d_out, int out_size, void* d_ws, size_t ws_size,
                              hipStream_t stream) {
    const float* x = (const float*)d_in[0];
    const float* Wf = (const float*)d_in[1];
    float* out = (float*)d_out;
    float* wsf = (float*)d_ws;
    float* losses = out + (size_t)B * C * N;

    // big path ws need (floats):
    //   xbt       [0,          16,777,216)   (33,554,432 us)
    //   xsq       [16,777,216, 16,908,288)
    //   proto_bf  [16,908,288, 17,170,432)   (524,288 us = 262,144 f)
    //   protoT_bf [17,170,432, 17,432,576)   (524,288 us = 262,144 f)
    //   Wb        [17,432,576, 17,440,768)   (16,384 us)
    //   p2        [17,440,768, 17,442,816)
    //   cparts    [17,442,816, 17,443,328)
    //   dparts    [17,443,328, 17,443,584)
    // total 17,443,584 f = 69,774,336 bytes
    const bool big = ws_size >= (size_t)69774336;

    if (big) {
        // Sbf/parts/Pbf live in d_out (all dead before k4f; k4f reads only ws).
        unsigned short* Sbf = (unsigned short*)out;                      // [0, 4,194,304) f
        float* parts = out + 4194304;                                    // [4,194,304, 8,388,608) f
        unsigned short* Pbf = (unsigned short*)(out + 8388608);          // [8,388,608, 12,582,912) f
        unsigned short* xbt = (unsigned short*)wsf;
        float* xsq = wsf + 16777216;
        unsigned short* proto_bf = (unsigned short*)(wsf + 16908288);
        unsigned short* protoT_bf = (unsigned short*)(wsf + 17170432);
        unsigned short* Wb = (unsigned short*)(wsf + 17432576);
        float* p2 = wsf + 17440768;
        float* cparts = wsf + 17442816;
        float* dparts = wsf + 17443328;

        kW_convert<<<dim3(64), 256, 0, stream>>>(Wf, Wb);
        k01<<<dim3(N / 64, B), 256, 0, stream>>>(x, Wb, xbt, Sbf, xsq);
        k2_softmax_n<<<dim3(M, B), 256, 0, stream>>>(Sbf, Pbf);
        k3_mfma<<<dim3(8, B), 256, 0, stream>>>(x, Pbf, parts);
        k3b_reduce<<<dim3(8, B), 256, 0, stream>>>(parts, proto_bf, protoT_bf, p2);
        k4f<<<dim3(N / 256, B), 512, 0, stream>>>(proto_bf, protoT_bf, xbt, p2, xsq,
                                                  out, cparts);
        k5_dis<<<dim3(8, B), 256, 0, stream>>>(proto_bf, p2, dparts);
        k6_final<<<1, 256, 0, stream>>>(cparts, dparts, losses);
    } else {
        // r3/r4-proven fallback: xbt in d_out (dead before k4b), pnm in ws region B
        unsigned short* xbt = (unsigned short*)d_out;
        unsigned short* Sbf = (unsigned short*)wsf;
        float* parts = wsf;
        unsigned short* Pbf = (unsigned short*)(wsf + 4194304);
        unsigned short* pnm = Pbf;
        float* xsq = wsf + 8388608;
        unsigned short* proto_bf = (unsigned short*)(wsf + 8519680);
        unsigned short* protoT_bf = (unsigned short*)(wsf + 8781824);
        unsigned short* Wb = (unsigned short*)(wsf + 9043968);
        float* p2 = wsf + 9052160;
        float* cparts = wsf + 9054208;
        float* dparts = wsf + 9054720;

        kW_convert<<<dim3(64), 256, 0, stream>>>(Wf, Wb);
        k01<<<dim3(N / 64, B), 256, 0, stream>>>(x, Wb, xbt, Sbf, xsq);
        k2_softmax_n<<<dim3(M, B), 256, 0, stream>>>(Sbf, Pbf);
        k3_mfma<<<dim3(8, B), 256, 0, stream>>>(x, Pbf, parts);
        k3b_reduce<<<dim3(8, B), 256, 0, stream>>>(parts, proto_bf, protoT_bf, p2);
        k4_score<<<dim3(N / 256, B), 256, 0, stream>>>(proto_bf, xbt, p2, xsq, pnm, cparts);
        k4b_mfma<<<dim3(N / 64, B), 256, 0, stream>>>(pnm, protoT_bf, out);
        k5_dis<<<dim3(8, B), 256, 0, stream>>>(proto_bf, p2, dparts);
        k6_final<<<1, 256, 0, stream>>>(cparts, dparts, losses);
    }
}

// Round 7
// 192.935 us; speedup vs baseline: 1.0090x; 1.0090x over previous
//
#include <hip/hip_runtime.h>
#include <math.h>

#define B 32
#define C 256
#define M 64
#define N 4096  // H*W

typedef __attribute__((ext_vector_type(8))) short s16x8;
typedef __attribute__((ext_vector_type(8))) __bf16 bf16x8;
typedef __attribute__((ext_vector_type(4))) float f32x4;
typedef __attribute__((ext_vector_type(4))) unsigned short u16x4;
typedef __attribute__((ext_vector_type(8))) unsigned short u16x8;

static constexpr float EPS = 1e-12f;

__device__ __forceinline__ unsigned short f2bf(float f) {
    unsigned u = __float_as_uint(f);
    u += 0x7FFFu + ((u >> 16) & 1u);  // RNE
    return (unsigned short)(u >> 16);
}
__device__ __forceinline__ float bf2f(unsigned short h) {
    return __uint_as_float((unsigned)h << 16);
}
__device__ __forceinline__ f32x4 MFMA(s16x8 a, s16x8 b, f32x4 c) {
    return __builtin_amdgcn_mfma_f32_16x16x32_bf16(
        __builtin_bit_cast(bf16x8, a), __builtin_bit_cast(bf16x8, b), c, 0, 0, 0);
}
__device__ __forceinline__ s16x8 cvt8(const f32x4 a, const f32x4 b) {
    bf16x8 h;
    h[0] = (__bf16)a[0]; h[1] = (__bf16)a[1]; h[2] = (__bf16)a[2]; h[3] = (__bf16)a[3];
    h[4] = (__bf16)b[0]; h[5] = (__bf16)b[1]; h[6] = (__bf16)b[2]; h[7] = (__bf16)b[3];
    return __builtin_bit_cast(s16x8, h);
}
// LDS column swizzle for the [n][c] bf16 tile (halfword units, flips bits 3-5 of c)
__device__ __forceinline__ int swz(int n) {
    return (((n >> 2) & 3) | ((n & 1) << 2)) << 3;
}

// ---------------------------------------------------------------------------
// K01: fused convert + transpose + logits. W converted f32->bf16 in-reg.
// ---------------------------------------------------------------------------
__global__ __launch_bounds__(256) void k01(const float* __restrict__ x,
                                           const float* __restrict__ Wf,
                                           unsigned short* __restrict__ xbt,
                                           unsigned short* __restrict__ Sb,
                                           float* __restrict__ xsq) {
    const int nb = blockIdx.x, b = blockIdx.y;
    const int t = threadIdx.x;
    __shared__ unsigned short tsT[64 * 256];
    __shared__ float xred[16][68];
    // ---- phase A ----
    const int nq = t & 15, cq = t >> 4;
    float part[4] = {0.f, 0.f, 0.f, 0.f};
    const float* xrow = x + (size_t)b * C * N + (size_t)nb * 64 + 4 * nq;
#pragma unroll
    for (int step = 0; step < 4; ++step) {
        const int c0 = cq * 4 + step * 64;
        f32x4 q[4];
#pragma unroll
        for (int i = 0; i < 4; ++i) q[i] = *(const f32x4*)(xrow + (size_t)(c0 + i) * N);
#pragma unroll
        for (int k = 0; k < 4; ++k) {
            const int n = 4 * nq + k;
            u16x4 h;
#pragma unroll
            for (int i = 0; i < 4; ++i) {
                part[k] += q[i][k] * q[i][k];
                h[i] = f2bf(q[i][k]);
            }
            *(u16x4*)(&tsT[n * 256 + (c0 ^ swz(n))]) = h;
        }
    }
#pragma unroll
    for (int k = 0; k < 4; ++k) xred[cq][4 * nq + k] = part[k];
    __syncthreads();
    if (t < 64) {
        float s = 0.f;
#pragma unroll
        for (int j = 0; j < 16; ++j) s += xred[j][t];
        xsq[(size_t)b * N + nb * 64 + t] = s;
    }
    // ---- phase B1: xbt coalesced write ----
    {
        const int l = t & 31, nh = t >> 5;
#pragma unroll
        for (int j = 0; j < 8; ++j) {
            const int n = nh + 8 * j;
            const int c0 = l * 8;
            const u16x8 v = *(const u16x8*)(&tsT[n * 256 + (c0 ^ swz(n))]);
            *(u16x8*)(xbt + ((size_t)b * N + nb * 64 + n) * C + c0) = v;
        }
    }
    // ---- phase B2: logits MFMA (W f32 -> bf16 in-reg) ----
    const int wv = t >> 6, lane = t & 63, li = lane & 15, lk = lane >> 4;
    const f32x4 zv = {0.f, 0.f, 0.f, 0.f};
    f32x4 acc[4] = {zv, zv, zv, zv};
    const float* wr = Wf + (size_t)(wv * 16 + li) * C + lk * 8;
#pragma unroll
    for (int c0 = 0; c0 < C; c0 += 32) {
        const s16x8 bfrag = cvt8(*(const f32x4*)(wr + c0), *(const f32x4*)(wr + c0 + 4));
#pragma unroll
        for (int s = 0; s < 4; ++s) {
            const int n = s * 16 + li;
            const s16x8 a = *(const s16x8*)(&tsT[n * 256 + ((lk * 8 + c0) ^ swz(n))]);
            acc[s] = MFMA(a, bfrag, acc[s]);
        }
    }
    unsigned short* Srow = Sb + ((size_t)b * M + wv * 16 + li) * N + nb * 64;
#pragma unroll
    for (int s = 0; s < 4; ++s) {
        u16x4 h;
#pragma unroll
        for (int r = 0; r < 4; ++r) h[r] = f2bf(acc[s][r]);
        *(u16x4*)(Srow + s * 16 + lk * 4) = h;
    }
}

// ---------------------------------------------------------------------------
// K2: softmax over n per (b,m); bf16 in -> bf16 out. (verified)
// ---------------------------------------------------------------------------
__global__ __launch_bounds__(256) void k2_softmax_n(const unsigned short* __restrict__ Sb,
                                                    unsigned short* __restrict__ Pb) {
    const int m = blockIdx.x, b = blockIdx.y;
    const unsigned short* col = Sb + ((size_t)b * M + m) * N;
    unsigned short* po = Pb + ((size_t)b * M + m) * N;
    const int t = threadIdx.x;
    float v[16];
    const u16x8 h0 = *(const u16x8*)(col + t * 16);
    const u16x8 h1 = *(const u16x8*)(col + t * 16 + 8);
#pragma unroll
    for (int i = 0; i < 8; ++i) v[i] = bf2f(h0[i]);
#pragma unroll
    for (int i = 0; i < 8; ++i) v[8 + i] = bf2f(h1[i]);
    float mx = -INFINITY;
#pragma unroll
    for (int i = 0; i < 16; ++i) mx = fmaxf(mx, v[i]);
#pragma unroll
    for (int off = 32; off >= 1; off >>= 1) mx = fmaxf(mx, __shfl_xor(mx, off));
    __shared__ float redm[4], reds[4];
    const int wave = t >> 6, lane = t & 63;
    if (lane == 0) redm[wave] = mx;
    __syncthreads();
    mx = fmaxf(fmaxf(redm[0], redm[1]), fmaxf(redm[2], redm[3]));
    float s = 0.f;
#pragma unroll
    for (int i = 0; i < 16; ++i) {
        v[i] = __expf(v[i] - mx);
        s += v[i];
    }
#pragma unroll
    for (int off = 32; off >= 1; off >>= 1) s += __shfl_xor(s, off);
    if (lane == 0) reds[wave] = s;
    __syncthreads();
    s = reds[0] + reds[1] + reds[2] + reds[3];
    const float inv = 1.f / s;
    u16x8 o0, o1;
#pragma unroll
    for (int i = 0; i < 8; ++i) o0[i] = f2bf(v[i] * inv);
#pragma unroll
    for (int i = 0; i < 8; ++i) o1[i] = f2bf(v[8 + i] * inv);
    *(u16x8*)(po + t * 16) = o0;
    *(u16x8*)(po + t * 16 + 8) = o1;
}

// ---------------------------------------------------------------------------
// K3: proto partials parts[b][ck][m][c] over 512-n chunks. (verified)
// ---------------------------------------------------------------------------
__global__ __launch_bounds__(256) void k3_mfma(const float* __restrict__ x,
                                               const unsigned short* __restrict__ Pb,
                                               float* __restrict__ parts) {
    const int ck = blockIdx.x, b = blockIdx.y;
    const int wv = threadIdx.x >> 6, lane = threadIdx.x & 63;
    const int li = lane & 15, lk = lane >> 4;
    const int c0w = wv * 64;
    const int nb = ck * 512;
    const f32x4 zv = {0.f, 0.f, 0.f, 0.f};
    f32x4 acc[4][4];
#pragma unroll
    for (int s = 0; s < 4; ++s)
#pragma unroll
        for (int u = 0; u < 4; ++u) acc[s][u] = zv;
    const float* ar = x + ((size_t)b * C + c0w + li) * N + nb + lk * 8;
    const unsigned short* br = Pb + ((size_t)b * M + li) * N + nb + lk * 8;
#pragma unroll 4
    for (int n0 = 0; n0 < 512; n0 += 32) {
        s16x8 af[4], bf_[4];
#pragma unroll
        for (int s = 0; s < 4; ++s) {
            const float* p = ar + (size_t)(s * 16) * N + n0;
            af[s] = cvt8(*(const f32x4*)p, *(const f32x4*)(p + 4));
        }
#pragma unroll
        for (int u = 0; u < 4; ++u) bf_[u] = *(const s16x8*)(br + (size_t)(u * 16) * N + n0);
#pragma unroll
        for (int s = 0; s < 4; ++s)
#pragma unroll
            for (int u = 0; u < 4; ++u) acc[s][u] = MFMA(af[s], bf_[u], acc[s][u]);
    }
    float* pp = parts + ((size_t)b * 8 + ck) * M * C;
#pragma unroll
    for (int s = 0; s < 4; ++s)
#pragma unroll
        for (int u = 0; u < 4; ++u)
            *(f32x4*)(pp + (size_t)(u * 16 + li) * C + c0w + s * 16 + lk * 4) = acc[s][u];
}

// ---------------------------------------------------------------------------
// K3b: reduce 8 chunks -> l2norm -> proto_bf [m][c], protoT_bf [c][m], p2.
// ---------------------------------------------------------------------------
__global__ __launch_bounds__(256) void k3b_reduce(const float* __restrict__ parts,
                                                  unsigned short* __restrict__ proto_bf,
                                                  unsigned short* __restrict__ protoT_bf,
                                                  float* __restrict__ p2) {
    const int mb = blockIdx.x, b = blockIdx.y;
    const int t = threadIdx.x;
    const int ml = t >> 5, cl = t & 31;
    const int m = mb * 8 + ml;
    const int c0 = cl * 8;
    float v[8] = {0.f, 0.f, 0.f, 0.f, 0.f, 0.f, 0.f, 0.f};
    const float* pbase = parts + (size_t)b * 8 * M * C + (size_t)m * C + c0;
#pragma unroll
    for (int ck = 0; ck < 8; ++ck) {
        const f32x4 q0 = *(const f32x4*)(pbase + (size_t)ck * M * C);
        const f32x4 q1 = *(const f32x4*)(pbase + (size_t)ck * M * C + 4);
#pragma unroll
        for (int j = 0; j < 4; ++j) { v[j] += q0[j]; v[4 + j] += q1[j]; }
    }
    float sq = 0.f;
#pragma unroll
    for (int j = 0; j < 8; ++j) sq += v[j] * v[j];
#pragma unroll
    for (int off = 16; off >= 1; off >>= 1) sq += __shfl_xor(sq, off);
    const float denom = fmaxf(sqrtf(sq), EPS);
    const float scale = 1.f / denom;
    if (cl == 0) p2[b * M + m] = sq / (denom * denom);
    u16x8 h;
#pragma unroll
    for (int j = 0; j < 8; ++j) h[j] = f2bf(v[j] * scale);
    *(u16x8*)(proto_bf + ((size_t)b * M + m) * C + c0) = h;
#pragma unroll
    for (int j = 0; j < 8; ++j)
        protoT_bf[((size_t)b * C + c0 + j) * M + m] = h[j];
}

// ---------------------------------------------------------------------------
// K4F2: fused score + softmax-m (norm folded into c-norm) + compact + PV +
// c-norm + store. 256 threads, 128 n/block, __launch_bounds__(256,2).
// Phase1: wave w owns 32 n. P (unnormalized exp) -> swizzled LDS.
// Phase2: wave (nq=w&1, ch=w>>1) owns 64n x 128c.
// Reads ONLY ws-resident buffers -> no race with out writes.
// ---------------------------------------------------------------------------
__global__ __launch_bounds__(256, 2) void k4f2(const unsigned short* __restrict__ proto_bf,
                                               const unsigned short* __restrict__ protoT_bf,
                                               const unsigned short* __restrict__ xbt,
                                               const float* __restrict__ p2,
                                               const float* __restrict__ xsq,
                                               float* __restrict__ out,
                                               float* __restrict__ cparts) {
    const int b = blockIdx.y;
    const int t = threadIdx.x;
    const int w = t >> 6, lane = t & 63, li = lane & 15, lk = lane >> 4;
    const int nblk = blockIdx.x * 128;
    __shared__ unsigned short p_lds[128 * 64];  // 16 KB; row nl, byte ^ ((nl&7)<<4)
    __shared__ float red2[2][128];
    __shared__ float red4[4];
    const f32x4 zv = {0.f, 0.f, 0.f, 0.f};
    // ---- phase 1: scores for n in [nblk + w*32, +32) ----
    f32x4 acc[4][2];
#pragma unroll
    for (int s = 0; s < 4; ++s)
#pragma unroll
        for (int u = 0; u < 2; ++u) acc[s][u] = zv;
    const unsigned short* ar = proto_bf + (size_t)b * M * C + (size_t)li * C + lk * 8;
    const unsigned short* br = xbt + ((size_t)b * N + nblk + w * 32 + li) * C + lk * 8;
#pragma unroll
    for (int c0 = 0; c0 < C; c0 += 32) {
        s16x8 af[4], bf_[2];
#pragma unroll
        for (int s = 0; s < 4; ++s) af[s] = *(const s16x8*)(ar + (size_t)(s * 16) * C + c0);
#pragma unroll
        for (int u = 0; u < 2; ++u) bf_[u] = *(const s16x8*)(br + (size_t)(u * 16) * C + c0);
#pragma unroll
        for (int s = 0; s < 4; ++s)
#pragma unroll
            for (int u = 0; u < 2; ++u) acc[s][u] = MFMA(af[s], bf_[u], acc[s][u]);
    }
    float csum = 0.f;
#pragma unroll
    for (int u = 0; u < 2; ++u) {
        const int n = nblk + w * 32 + u * 16 + li;
        const int nl = w * 32 + u * 16 + li;
        float vmax = -INFINITY;
#pragma unroll
        for (int s = 0; s < 4; ++s)
#pragma unroll
            for (int r = 0; r < 4; ++r) vmax = fmaxf(vmax, acc[s][u][r]);
        vmax = fmaxf(vmax, __shfl_xor(vmax, 16));
        vmax = fmaxf(vmax, __shfl_xor(vmax, 32));
        int t1 = 1 << 30;
#pragma unroll
        for (int s = 0; s < 4; ++s)
#pragma unroll
            for (int r = 0; r < 4; ++r)
                if (acc[s][u][r] == vmax) t1 = min(t1, s * 16 + lk * 4 + r);
        t1 = min(t1, __shfl_xor(t1, 16));
        t1 = min(t1, __shfl_xor(t1, 32));
        // unnormalized exp: the 1/sum cancels in the downstream L2-normalize
#pragma unroll
        for (int s = 0; s < 4; ++s) {
            u16x4 h;
#pragma unroll
            for (int r = 0; r < 4; ++r) h[r] = f2bf(__expf(acc[s][u][r] - vmax));
            const unsigned off =
                (unsigned)((nl * 128 + ((s * 16 + lk * 4) << 1)) ^ ((nl & 7) << 4));
            *(u16x4*)((char*)p_lds + off) = h;
        }
        if (lk == 0) csum += xsq[(size_t)b * N + n] - 2.f * vmax + p2[b * M + t1];
    }
#pragma unroll
    for (int off = 32; off >= 1; off >>= 1) csum += __shfl_xor(csum, off);
    if (lane == 0) red4[w] = csum;
    __syncthreads();
    if (t == 0) cparts[b * 32 + blockIdx.x] = red4[0] + red4[1] + red4[2] + red4[3];
    // ---- phase 2: PV ----
    const int nq = w & 1, ch = w >> 1;
    f32x4 a2[4][8];
#pragma unroll
    for (int s = 0; s < 4; ++s)
#pragma unroll
        for (int u = 0; u < 8; ++u) a2[s][u] = zv;
    const unsigned short* br2 = protoT_bf + ((size_t)b * C + ch * 128 + li) * M + lk * 8;
#pragma unroll
    for (int m0 = 0; m0 < M; m0 += 32) {
        s16x8 af2[4], bf2[8];
#pragma unroll
        for (int s = 0; s < 4; ++s) {
            const int nl = nq * 64 + s * 16 + li;
            const unsigned off =
                (unsigned)((nl * 128 + ((m0 + lk * 8) << 1)) ^ ((nl & 7) << 4));
            af2[s] = *(const s16x8*)((const char*)p_lds + off);
        }
#pragma unroll
        for (int u = 0; u < 8; ++u)
            bf2[u] = *(const s16x8*)(br2 + (size_t)(u * 16) * M + m0);
#pragma unroll
        for (int s = 0; s < 4; ++s)
#pragma unroll
            for (int u = 0; u < 8; ++u) a2[s][u] = MFMA(af2[s], bf2[u], a2[s][u]);
    }
    float ssq[4][4];
#pragma unroll
    for (int s = 0; s < 4; ++s)
#pragma unroll
        for (int r = 0; r < 4; ++r) {
            float sum = 0.f;
#pragma unroll
            for (int u = 0; u < 8; ++u) sum += a2[s][u][r] * a2[s][u][r];
#pragma unroll
            for (int off = 8; off >= 1; off >>= 1) sum += __shfl_xor(sum, off);
            ssq[s][r] = sum;
        }
    if (li == 0) {
#pragma unroll
        for (int s = 0; s < 4; ++s)
#pragma unroll
            for (int r = 0; r < 4; ++r)
                red2[ch][nq * 64 + s * 16 + lk * 4 + r] = ssq[s][r];
    }
    __syncthreads();
    float scl[4][4];
#pragma unroll
    for (int s = 0; s < 4; ++s)
#pragma unroll
        for (int r = 0; r < 4; ++r) {
            const int nl = nq * 64 + s * 16 + lk * 4 + r;
            scl[s][r] = 1.f / fmaxf(sqrtf(red2[0][nl] + red2[1][nl]), EPS);
        }
    float* ob = out + (size_t)b * C * N;
#pragma unroll
    for (int s = 0; s < 4; ++s)
#pragma unroll
        for (int u = 0; u < 8; ++u) {
            const int c = ch * 128 + u * 16 + li;
            f32x4 q;
#pragma unroll
            for (int r = 0; r < 4; ++r) q[r] = a2[s][u][r] * scl[s][r];
            *(f32x4*)(ob + (size_t)c * N + nblk + nq * 64 + s * 16 + lk * 4) = q;
        }
}

// ---------------------------------------------------------------------------
// K4 (fallback): score + softmax-m (unnormalized) + compact -> pnm global.
// ---------------------------------------------------------------------------
__global__ __launch_bounds__(256) void k4_score(const unsigned short* __restrict__ proto_bf,
                                                const unsigned short* __restrict__ xbt,
                                                const float* __restrict__ p2,
                                                const float* __restrict__ xsq,
                                                unsigned short* __restrict__ pnm,
                                                float* __restrict__ cparts) {
    const int b = blockIdx.y;
    const int wv = threadIdx.x >> 6, lane = threadIdx.x & 63;
    const int li = lane & 15, lk = lane >> 4;
    const int nbase = blockIdx.x * 256 + wv * 64;
    const f32x4 zv = {0.f, 0.f, 0.f, 0.f};
    f32x4 acc[4][4];
#pragma unroll
    for (int s = 0; s < 4; ++s)
#pragma unroll
        for (int u = 0; u < 4; ++u) acc[s][u] = zv;
    const unsigned short* ar = proto_bf + ((size_t)b * M + li) * C + lk * 8;
    const unsigned short* br = xbt + ((size_t)b * N + nbase + li) * C + lk * 8;
#pragma unroll
    for (int c0 = 0; c0 < C; c0 += 32) {
        s16x8 af[4], bf_[4];
#pragma unroll
        for (int s = 0; s < 4; ++s) af[s] = *(const s16x8*)(ar + (size_t)(s * 16) * C + c0);
#pragma unroll
        for (int u = 0; u < 4; ++u) bf_[u] = *(const s16x8*)(br + (size_t)(u * 16) * C + c0);
#pragma unroll
        for (int s = 0; s < 4; ++s)
#pragma unroll
            for (int u = 0; u < 4; ++u) acc[s][u] = MFMA(af[s], bf_[u], acc[s][u]);
    }
    float csum = 0.f;
#pragma unroll
    for (int u = 0; u < 4; ++u) {
        const int n = nbase + u * 16 + li;
        float vmax = -INFINITY;
#pragma unroll
        for (int s = 0; s < 4; ++s)
#pragma unroll
            for (int r = 0; r < 4; ++r) vmax = fmaxf(vmax, acc[s][u][r]);
        vmax = fmaxf(vmax, __shfl_xor(vmax, 16));
        vmax = fmaxf(vmax, __shfl_xor(vmax, 32));
        int t1 = 1 << 30;
#pragma unroll
        for (int s = 0; s < 4; ++s)
#pragma unroll
            for (int r = 0; r < 4; ++r)
                if (acc[s][u][r] == vmax) t1 = min(t1, s * 16 + lk * 4 + r);
        t1 = min(t1, __shfl_xor(t1, 16));
        t1 = min(t1, __shfl_xor(t1, 32));
        unsigned short* prow = pnm + ((size_t)b * N + n) * M;
#pragma unroll
        for (int s = 0; s < 4; ++s) {
            u16x4 h;
#pragma unroll
            for (int r = 0; r < 4; ++r) h[r] = f2bf(__expf(acc[s][u][r] - vmax));
            *(u16x4*)(prow + s * 16 + lk * 4) = h;
        }
        if (lk == 0) csum += xsq[(size_t)b * N + n] - 2.f * vmax + p2[b * M + t1];
    }
#pragma unroll
    for (int off = 32; off >= 1; off >>= 1) csum += __shfl_xor(csum, off);
    __shared__ float red[4];
    if (lane == 0) red[wv] = csum;
    __syncthreads();
    if (threadIdx.x == 0)
        cparts[b * 16 + blockIdx.x] = red[0] + red[1] + red[2] + red[3];
}

// ---------------------------------------------------------------------------
// K4b (fallback): out = l2norm_c(sum_m p[n][m]*protoT[c][m]).
// ---------------------------------------------------------------------------
__global__ __launch_bounds__(256) void k4b_mfma(const unsigned short* __restrict__ pnm,
                                                const unsigned short* __restrict__ protoT_bf,
                                                float* __restrict__ out) {
    const int b = blockIdx.y;
    const int wv = threadIdx.x >> 6, lane = threadIdx.x & 63;
    const int li = lane & 15, lk = lane >> 4;
    const int n0 = blockIdx.x * 64;
    const int cb = wv * 64;
    const f32x4 zv = {0.f, 0.f, 0.f, 0.f};
    f32x4 acc[4][4];
#pragma unroll
    for (int s = 0; s < 4; ++s)
#pragma unroll
        for (int u = 0; u < 4; ++u) acc[s][u] = zv;
    const unsigned short* ar = pnm + ((size_t)b * N + n0 + li) * M + lk * 8;
    const unsigned short* br = protoT_bf + ((size_t)b * C + cb + li) * M + lk * 8;
#pragma unroll
    for (int m0 = 0; m0 < M; m0 += 32) {
        s16x8 af[4], bf_[4];
#pragma unroll
        for (int s = 0; s < 4; ++s) af[s] = *(const s16x8*)(ar + (size_t)(s * 16) * M + m0);
#pragma unroll
        for (int u = 0; u < 4; ++u) bf_[u] = *(const s16x8*)(br + (size_t)(u * 16) * M + m0);
#pragma unroll
        for (int s = 0; s < 4; ++s)
#pragma unroll
            for (int u = 0; u < 4; ++u) acc[s][u] = MFMA(af[s], bf_[u], acc[s][u]);
    }
    __shared__ float ls[4][64];
    __shared__ float ls2[64];
    float psq[4][4];
#pragma unroll
    for (int s = 0; s < 4; ++s)
#pragma unroll
        for (int r = 0; r < 4; ++r) {
            float sum = 0.f;
#pragma unroll
            for (int u = 0; u < 4; ++u) sum += acc[s][u][r] * acc[s][u][r];
#pragma unroll
            for (int off = 8; off >= 1; off >>= 1) sum += __shfl_xor(sum, off);
            psq[s][r] = sum;
        }
    if (li == 0) {
#pragma unroll
        for (int s = 0; s < 4; ++s)
#pragma unroll
            for (int r = 0; r < 4; ++r) ls[wv][s * 16 + lk * 4 + r] = psq[s][r];
    }
    __syncthreads();
    if (threadIdx.x < 64) {
        const int tt = threadIdx.x;
        const float tot = ls[0][tt] + ls[1][tt] + ls[2][tt] + ls[3][tt];
        ls2[tt] = 1.f / fmaxf(sqrtf(tot), EPS);
    }
    __syncthreads();
    float scl[4][4];
#pragma unroll
    for (int s = 0; s < 4; ++s)
#pragma unroll
        for (int r = 0; r < 4; ++r) scl[s][r] = ls2[s * 16 + lk * 4 + r];
    float* ob = out + (size_t)b * C * N;
#pragma unroll
    for (int s = 0; s < 4; ++s)
#pragma unroll
        for (int u = 0; u < 4; ++u) {
            f32x4 q;
#pragma unroll
            for (int r = 0; r < 4; ++r) q[r] = acc[s][u][r] * scl[s][r];
            *(f32x4*)(ob + (size_t)(cb + u * 16 + li) * N + n0 + s * 16 + lk * 4) = q;
        }
}

// ---------------------------------------------------------------------------
// K5 / K6: losses.
// ---------------------------------------------------------------------------
__global__ __launch_bounds__(256) void k5_dis(const unsigned short* __restrict__ proto_bf,
                                              const float* __restrict__ p2,
                                              float* __restrict__ dparts) {
    const int q = blockIdx.x;
    const int b = blockIdx.y;
    const unsigned short* pr = proto_bf + (size_t)b * M * C;
    __shared__ float pl[M * C];
    for (int idx = threadIdx.x; idx < M * C; idx += 256) {
        int m = idx >> 8, c = idx & 255;
        pl[m * 256 + (c ^ (m & 31))] = bf2f(pr[idx]);
    }
    __syncthreads();
    float sum = 0.f;
    for (int k = 0; k < 2; ++k) {
        const int pair = q * 512 + k * 256 + threadIdx.x;
        const int i = pair >> 6, j = pair & 63;
        if (j > i) {
            float g = 0.f;
#pragma unroll 8
            for (int c = 0; c < C; ++c)
                g += pl[i * 256 + (c ^ (i & 31))] * pl[j * 256 + (c ^ (j & 31))];
            const float d = 1.f - (p2[b * M + i] + p2[b * M + j] - 2.f * g);
            sum += fmaxf(d, 0.f);
        }
    }
#pragma unroll
    for (int off = 32; off >= 1; off >>= 1) sum += __shfl_xor(sum, off);
    __shared__ float red[4];
    const int wave = threadIdx.x >> 6, lane = threadIdx.x & 63;
    if (lane == 0) red[wave] = sum;
    __syncthreads();
    if (threadIdx.x == 0) dparts[b * 8 + q] = red[0] + red[1] + red[2] + red[3];
}

__global__ __launch_bounds__(256) void k6_final(const float* __restrict__ cparts, int ncp,
                                                const float* __restrict__ dparts,
                                                float* __restrict__ losses) {
    const int t = threadIdx.x;
    float cs = 0.f;
    for (int i = t; i < ncp; i += 256) cs += cparts[i];
    float ds = dparts[t];
#pragma unroll
    for (int off = 32; off >= 1; off >>= 1) {
        cs += __shfl_xor(cs, off);
        ds += __shfl_xor(ds, off);
    }
    __shared__ float rc[4], rd[4];
    const int wave = t >> 6, lane = t & 63;
    if (lane == 0) { rc[wave] = cs; rd[wave] = ds; }
    __syncthreads();
    if (t == 0) {
        const float ctot = rc[0] + rc[1] + rc[2] + rc[3];
        const float dtot = rd[0] + rd[1] + rd[2] + rd[3];
        losses[0] = ctot / ((float)B * (float)N * (float)C);
        losses[1] = dtot * (2.f / (float)(M * (M - 1))) / (float)B;
    }
}

extern "C" void kernel_launch(void* const* d_in, const int* in_sizes, int n_in,
                              void* d_out, int out_size, void* d_ws, size_t ws_size,
                              hipStream_t stream) {
    const float* x = (const float*)d_in[0];
    const float* Wf = (const float*)d_in[1];
    float* out = (float*)d_out;
    float* wsf = (float*)d_ws;
    float* losses = out + (size_t)B * C * N;

    // big path ws need (floats):
    //   xbt       [0,          16,777,216)   (33,554,432 us)
    //   xsq       [16,777,216, 16,908,288)
    //   proto_bf  [16,908,288, 17,170,432)   (524,288 us)
    //   protoT_bf [17,170,432, 17,432,576)   (524,288 us)
    //   p2        [17,432,576, 17,434,624)
    //   cparts    [17,434,624, 17,435,648)   (1024)
    //   dparts    [17,435,648, 17,435,904)
    // total 17,435,904 f = 69,743,616 bytes
    const bool big = ws_size >= (size_t)69743616;

    if (big) {
        // Sbf/parts/Pbf live in d_out (all dead before k4f2; k4f2 reads only ws).
        unsigned short* Sbf = (unsigned short*)out;                 // [0, 4,194,304) f
        float* parts = out + 4194304;                               // [4,194,304, 8,388,608) f
        unsigned short* Pbf = (unsigned short*)(out + 8388608);     // [8,388,608, 12,582,912) f
        unsigned short* xbt = (unsigned short*)wsf;
        float* xsq = wsf + 16777216;
        unsigned short* proto_bf = (unsigned short*)(wsf + 16908288);
        unsigned short* protoT_bf = (unsigned short*)(wsf + 17170432);
        float* p2 = wsf + 17432576;
        float* cparts = wsf + 17434624;
        float* dparts = wsf + 17435648;

        k01<<<dim3(N / 64, B), 256, 0, stream>>>(x, Wf, xbt, Sbf, xsq);
        k2_softmax_n<<<dim3(M, B), 256, 0, stream>>>(Sbf, Pbf);
        k3_mfma<<<dim3(8, B), 256, 0, stream>>>(x, Pbf, parts);
        k3b_reduce<<<dim3(8, B), 256, 0, stream>>>(parts, proto_bf, protoT_bf, p2);
        k4f2<<<dim3(N / 128, B), 256, 0, stream>>>(proto_bf, protoT_bf, xbt, p2, xsq,
                                                   out, cparts);
        k5_dis<<<dim3(8, B), 256, 0, stream>>>(proto_bf, p2, dparts);
        k6_final<<<1, 256, 0, stream>>>(cparts, B * 32, dparts, losses);
    } else {
        // proven fallback: xbt in d_out (dead before k4b), pnm in ws region B
        unsigned short* xbt = (unsigned short*)d_out;
        unsigned short* Sbf = (unsigned short*)wsf;
        float* parts = wsf;
        unsigned short* Pbf = (unsigned short*)(wsf + 4194304);
        unsigned short* pnm = Pbf;
        float* xsq = wsf + 8388608;
        unsigned short* proto_bf = (unsigned short*)(wsf + 8519680);
        unsigned short* protoT_bf = (unsigned short*)(wsf + 8781824);
        float* p2 = wsf + 9052160;
        float* cparts = wsf + 9054208;
        float* dparts = wsf + 9054720;

        k01<<<dim3(N / 64, B), 256, 0, stream>>>(x, Wf, xbt, Sbf, xsq);
        k2_softmax_n<<<dim3(M, B), 256, 0, stream>>>(Sbf, Pbf);
        k3_mfma<<<dim3(8, B), 256, 0, stream>>>(x, Pbf, parts);
        k3b_reduce<<<dim3(8, B), 256, 0, stream>>>(parts, proto_bf, protoT_bf, p2);
        k4_score<<<dim3(N / 256, B), 256, 0, stream>>>(proto_bf, xbt, p2, xsq, pnm, cparts);
        k4b_mfma<<<dim3(N / 64, B), 256, 0, stream>>>(pnm, protoT_bf, out);
        k5_dis<<<dim3(8, B), 256, 0, stream>>>(proto_bf, p2, dparts);
        k6_final<<<1, 256, 0, stream>>>(cparts, B * 16, dparts, losses);
    }
}

// Round 8
// 173.400 us; speedup vs baseline: 1.1227x; 1.1127x over previous
//
#include <hip/hip_runtime.h>
#include <math.h>

#define B 32
#define C 256
#define M 64
#define N 4096  // H*W

typedef __attribute__((ext_vector_type(8))) short s16x8;
typedef __attribute__((ext_vector_type(8))) __bf16 bf16x8;
typedef __attribute__((ext_vector_type(4))) __bf16 bf16x4;
typedef __attribute__((ext_vector_type(4))) float f32x4;
typedef __attribute__((ext_vector_type(4))) unsigned short u16x4;
typedef __attribute__((ext_vector_type(8))) unsigned short u16x8;

static constexpr float EPS = 1e-12f;

__device__ __forceinline__ unsigned short b16(float f) {
    __bf16 h = (__bf16)f;  // v_cvt_pk_bf16_f32 (RNE), compiler-fused
    return __builtin_bit_cast(unsigned short, h);
}
__device__ __forceinline__ float bf2f(unsigned short h) {
    return __uint_as_float((unsigned)h << 16);
}
__device__ __forceinline__ f32x4 MFMA(s16x8 a, s16x8 b, f32x4 c) {
    return __builtin_amdgcn_mfma_f32_16x16x32_bf16(
        __builtin_bit_cast(bf16x8, a), __builtin_bit_cast(bf16x8, b), c, 0, 0, 0);
}
__device__ __forceinline__ s16x8 cvt8(const f32x4 a, const f32x4 b) {
    bf16x8 h;
    h[0] = (__bf16)a[0]; h[1] = (__bf16)a[1]; h[2] = (__bf16)a[2]; h[3] = (__bf16)a[3];
    h[4] = (__bf16)b[0]; h[5] = (__bf16)b[1]; h[6] = (__bf16)b[2]; h[7] = (__bf16)b[3];
    return __builtin_bit_cast(s16x8, h);
}
// LDS column swizzle for the [n][c] bf16 tile (halfword units, flips bits 3-5 of c)
__device__ __forceinline__ int swz(int n) {
    return (((n >> 2) & 3) | ((n & 1) << 2)) << 3;
}

// ---------------------------------------------------------------------------
// K01: fused convert + transpose + logits. W converted f32->bf16 in-reg.
// All f32->bf16 via hw cvt_pk (plain casts).
// ---------------------------------------------------------------------------
__global__ __launch_bounds__(256) void k01(const float* __restrict__ x,
                                           const float* __restrict__ Wf,
                                           unsigned short* __restrict__ xbt,
                                           unsigned short* __restrict__ Sb,
                                           float* __restrict__ xsq) {
    const int nb = blockIdx.x, b = blockIdx.y;
    const int t = threadIdx.x;
    __shared__ unsigned short tsT[64 * 256];
    __shared__ float xred[16][68];
    // ---- phase A: load 4c x 4n register blocks, cvt, stage to LDS ----
    const int nq = t & 15, cq = t >> 4;
    float part[4] = {0.f, 0.f, 0.f, 0.f};
    const float* xrow = x + (size_t)b * C * N + (size_t)nb * 64 + 4 * nq;
#pragma unroll
    for (int step = 0; step < 4; ++step) {
        const int c0 = cq * 4 + step * 64;
        f32x4 q[4];
#pragma unroll
        for (int i = 0; i < 4; ++i) q[i] = *(const f32x4*)(xrow + (size_t)(c0 + i) * N);
#pragma unroll
        for (int k = 0; k < 4; ++k) {
            const int n = 4 * nq + k;
            bf16x4 hb;
#pragma unroll
            for (int i = 0; i < 4; ++i) {
                part[k] += q[i][k] * q[i][k];
                hb[i] = (__bf16)q[i][k];
            }
            *(u16x4*)(&tsT[n * 256 + (c0 ^ swz(n))]) = __builtin_bit_cast(u16x4, hb);
        }
    }
#pragma unroll
    for (int k = 0; k < 4; ++k) xred[cq][4 * nq + k] = part[k];
    __syncthreads();
    if (t < 64) {
        float s = 0.f;
#pragma unroll
        for (int j = 0; j < 16; ++j) s += xred[j][t];
        xsq[(size_t)b * N + nb * 64 + t] = s;
    }
    // ---- phase B1: xbt coalesced write ----
    {
        const int l = t & 31, nh = t >> 5;
#pragma unroll
        for (int j = 0; j < 8; ++j) {
            const int n = nh + 8 * j;
            const int c0 = l * 8;
            const u16x8 v = *(const u16x8*)(&tsT[n * 256 + (c0 ^ swz(n))]);
            *(u16x8*)(xbt + ((size_t)b * N + nb * 64 + n) * C + c0) = v;
        }
    }
    // ---- phase B2: logits MFMA (W f32 -> bf16 in-reg) ----
    const int wv = t >> 6, lane = t & 63, li = lane & 15, lk = lane >> 4;
    const f32x4 zv = {0.f, 0.f, 0.f, 0.f};
    f32x4 acc[4] = {zv, zv, zv, zv};
    const float* wr = Wf + (size_t)(wv * 16 + li) * C + lk * 8;
#pragma unroll
    for (int c0 = 0; c0 < C; c0 += 32) {
        const s16x8 bfrag = cvt8(*(const f32x4*)(wr + c0), *(const f32x4*)(wr + c0 + 4));
#pragma unroll
        for (int s = 0; s < 4; ++s) {
            const int n = s * 16 + li;
            const s16x8 a = *(const s16x8*)(&tsT[n * 256 + ((lk * 8 + c0) ^ swz(n))]);
            acc[s] = MFMA(a, bfrag, acc[s]);
        }
    }
    unsigned short* Srow = Sb + ((size_t)b * M + wv * 16 + li) * N + nb * 64;
#pragma unroll
    for (int s = 0; s < 4; ++s) {
        bf16x4 h;
#pragma unroll
        for (int r = 0; r < 4; ++r) h[r] = (__bf16)acc[s][r];
        *(u16x4*)(Srow + s * 16 + lk * 4) = __builtin_bit_cast(u16x4, h);
    }
}

// ---------------------------------------------------------------------------
// K2: softmax over n per (b,m); bf16 in -> bf16 out.
// ---------------------------------------------------------------------------
__global__ __launch_bounds__(256) void k2_softmax_n(const unsigned short* __restrict__ Sb,
                                                    unsigned short* __restrict__ Pb) {
    const int m = blockIdx.x, b = blockIdx.y;
    const unsigned short* col = Sb + ((size_t)b * M + m) * N;
    unsigned short* po = Pb + ((size_t)b * M + m) * N;
    const int t = threadIdx.x;
    float v[16];
    const u16x8 h0 = *(const u16x8*)(col + t * 16);
    const u16x8 h1 = *(const u16x8*)(col + t * 16 + 8);
#pragma unroll
    for (int i = 0; i < 8; ++i) v[i] = bf2f(h0[i]);
#pragma unroll
    for (int i = 0; i < 8; ++i) v[8 + i] = bf2f(h1[i]);
    float mx = -INFINITY;
#pragma unroll
    for (int i = 0; i < 16; ++i) mx = fmaxf(mx, v[i]);
#pragma unroll
    for (int off = 32; off >= 1; off >>= 1) mx = fmaxf(mx, __shfl_xor(mx, off));
    __shared__ float redm[4], reds[4];
    const int wave = t >> 6, lane = t & 63;
    if (lane == 0) redm[wave] = mx;
    __syncthreads();
    mx = fmaxf(fmaxf(redm[0], redm[1]), fmaxf(redm[2], redm[3]));
    float s = 0.f;
#pragma unroll
    for (int i = 0; i < 16; ++i) {
        v[i] = __expf(v[i] - mx);
        s += v[i];
    }
#pragma unroll
    for (int off = 32; off >= 1; off >>= 1) s += __shfl_xor(s, off);
    if (lane == 0) reds[wave] = s;
    __syncthreads();
    s = reds[0] + reds[1] + reds[2] + reds[3];
    const float inv = 1.f / s;
    bf16x8 o0, o1;
#pragma unroll
    for (int i = 0; i < 8; ++i) o0[i] = (__bf16)(v[i] * inv);
#pragma unroll
    for (int i = 0; i < 8; ++i) o1[i] = (__bf16)(v[8 + i] * inv);
    *(u16x8*)(po + t * 16) = __builtin_bit_cast(u16x8, o0);
    *(u16x8*)(po + t * 16 + 8) = __builtin_bit_cast(u16x8, o1);
}

// ---------------------------------------------------------------------------
// K3: proto partials parts[b][ck][m][c] over 512-n chunks. (verified)
// ---------------------------------------------------------------------------
__global__ __launch_bounds__(256) void k3_mfma(const float* __restrict__ x,
                                               const unsigned short* __restrict__ Pb,
                                               float* __restrict__ parts) {
    const int ck = blockIdx.x, b = blockIdx.y;
    const int wv = threadIdx.x >> 6, lane = threadIdx.x & 63;
    const int li = lane & 15, lk = lane >> 4;
    const int c0w = wv * 64;
    const int nb = ck * 512;
    const f32x4 zv = {0.f, 0.f, 0.f, 0.f};
    f32x4 acc[4][4];
#pragma unroll
    for (int s = 0; s < 4; ++s)
#pragma unroll
        for (int u = 0; u < 4; ++u) acc[s][u] = zv;
    const float* ar = x + ((size_t)b * C + c0w + li) * N + nb + lk * 8;
    const unsigned short* br = Pb + ((size_t)b * M + li) * N + nb + lk * 8;
#pragma unroll 4
    for (int n0 = 0; n0 < 512; n0 += 32) {
        s16x8 af[4], bf_[4];
#pragma unroll
        for (int s = 0; s < 4; ++s) {
            const float* p = ar + (size_t)(s * 16) * N + n0;
            af[s] = cvt8(*(const f32x4*)p, *(const f32x4*)(p + 4));
        }
#pragma unroll
        for (int u = 0; u < 4; ++u) bf_[u] = *(const s16x8*)(br + (size_t)(u * 16) * N + n0);
#pragma unroll
        for (int s = 0; s < 4; ++s)
#pragma unroll
            for (int u = 0; u < 4; ++u) acc[s][u] = MFMA(af[s], bf_[u], acc[s][u]);
    }
    float* pp = parts + ((size_t)b * 8 + ck) * M * C;
#pragma unroll
    for (int s = 0; s < 4; ++s)
#pragma unroll
        for (int u = 0; u < 4; ++u)
            *(f32x4*)(pp + (size_t)(u * 16 + li) * C + c0w + s * 16 + lk * 4) = acc[s][u];
}

// ---------------------------------------------------------------------------
// K3b: reduce 8 chunks -> l2norm -> proto_bf [m][c], protoT_bf [c][m], p2.
// ---------------------------------------------------------------------------
__global__ __launch_bounds__(256) void k3b_reduce(const float* __restrict__ parts,
                                                  unsigned short* __restrict__ proto_bf,
                                                  unsigned short* __restrict__ protoT_bf,
                                                  float* __restrict__ p2) {
    const int mb = blockIdx.x, b = blockIdx.y;
    const int t = threadIdx.x;
    const int ml = t >> 5, cl = t & 31;
    const int m = mb * 8 + ml;
    const int c0 = cl * 8;
    float v[8] = {0.f, 0.f, 0.f, 0.f, 0.f, 0.f, 0.f, 0.f};
    const float* pbase = parts + (size_t)b * 8 * M * C + (size_t)m * C + c0;
#pragma unroll
    for (int ck = 0; ck < 8; ++ck) {
        const f32x4 q0 = *(const f32x4*)(pbase + (size_t)ck * M * C);
        const f32x4 q1 = *(const f32x4*)(pbase + (size_t)ck * M * C + 4);
#pragma unroll
        for (int j = 0; j < 4; ++j) { v[j] += q0[j]; v[4 + j] += q1[j]; }
    }
    float sq = 0.f;
#pragma unroll
    for (int j = 0; j < 8; ++j) sq += v[j] * v[j];
#pragma unroll
    for (int off = 16; off >= 1; off >>= 1) sq += __shfl_xor(sq, off);
    const float denom = fmaxf(sqrtf(sq), EPS);
    const float scale = 1.f / denom;
    if (cl == 0) p2[b * M + m] = sq / (denom * denom);
    bf16x8 h;
#pragma unroll
    for (int j = 0; j < 8; ++j) h[j] = (__bf16)(v[j] * scale);
    const u16x8 hu = __builtin_bit_cast(u16x8, h);
    *(u16x8*)(proto_bf + ((size_t)b * M + m) * C + c0) = hu;
#pragma unroll
    for (int j = 0; j < 8; ++j)
        protoT_bf[((size_t)b * C + c0 + j) * M + m] = hu[j];
}

// ---------------------------------------------------------------------------
// K4: score + softmax-m (unnormalized; 1/sum cancels in L2-norm) + compact
// partials -> pnm bf16 [b][n][m].
// ---------------------------------------------------------------------------
__global__ __launch_bounds__(256) void k4_score(const unsigned short* __restrict__ proto_bf,
                                                const unsigned short* __restrict__ xbt,
                                                const float* __restrict__ p2,
                                                const float* __restrict__ xsq,
                                                unsigned short* __restrict__ pnm,
                                                float* __restrict__ cparts) {
    const int b = blockIdx.y;
    const int wv = threadIdx.x >> 6, lane = threadIdx.x & 63;
    const int li = lane & 15, lk = lane >> 4;
    const int nbase = blockIdx.x * 256 + wv * 64;
    const f32x4 zv = {0.f, 0.f, 0.f, 0.f};
    f32x4 acc[4][4];
#pragma unroll
    for (int s = 0; s < 4; ++s)
#pragma unroll
        for (int u = 0; u < 4; ++u) acc[s][u] = zv;
    const unsigned short* ar = proto_bf + ((size_t)b * M + li) * C + lk * 8;
    const unsigned short* br = xbt + ((size_t)b * N + nbase + li) * C + lk * 8;
#pragma unroll
    for (int c0 = 0; c0 < C; c0 += 32) {
        s16x8 af[4], bf_[4];
#pragma unroll
        for (int s = 0; s < 4; ++s) af[s] = *(const s16x8*)(ar + (size_t)(s * 16) * C + c0);
#pragma unroll
        for (int u = 0; u < 4; ++u) bf_[u] = *(const s16x8*)(br + (size_t)(u * 16) * C + c0);
#pragma unroll
        for (int s = 0; s < 4; ++s)
#pragma unroll
            for (int u = 0; u < 4; ++u) acc[s][u] = MFMA(af[s], bf_[u], acc[s][u]);
    }
    float csum = 0.f;
#pragma unroll
    for (int u = 0; u < 4; ++u) {
        const int n = nbase + u * 16 + li;
        float vmax = -INFINITY;
#pragma unroll
        for (int s = 0; s < 4; ++s)
#pragma unroll
            for (int r = 0; r < 4; ++r) vmax = fmaxf(vmax, acc[s][u][r]);
        vmax = fmaxf(vmax, __shfl_xor(vmax, 16));
        vmax = fmaxf(vmax, __shfl_xor(vmax, 32));
        int t1 = 1 << 30;
#pragma unroll
        for (int s = 0; s < 4; ++s)
#pragma unroll
            for (int r = 0; r < 4; ++r)
                if (acc[s][u][r] == vmax) t1 = min(t1, s * 16 + lk * 4 + r);
        t1 = min(t1, __shfl_xor(t1, 16));
        t1 = min(t1, __shfl_xor(t1, 32));
        unsigned short* prow = pnm + ((size_t)b * N + n) * M;
#pragma unroll
        for (int s = 0; s < 4; ++s) {
            bf16x4 h;
#pragma unroll
            for (int r = 0; r < 4; ++r) h[r] = (__bf16)__expf(acc[s][u][r] - vmax);
            *(u16x4*)(prow + s * 16 + lk * 4) = __builtin_bit_cast(u16x4, h);
        }
        if (lk == 0) csum += xsq[(size_t)b * N + n] - 2.f * vmax + p2[b * M + t1];
    }
#pragma unroll
    for (int off = 32; off >= 1; off >>= 1) csum += __shfl_xor(csum, off);
    __shared__ float red[4];
    if (lane == 0) red[wv] = csum;
    __syncthreads();
    if (threadIdx.x == 0)
        cparts[b * 16 + blockIdx.x] = red[0] + red[1] + red[2] + red[3];
}

// ---------------------------------------------------------------------------
// K4b: out = l2norm_c(sum_m p[n][m]*protoT[c][m]).
// ---------------------------------------------------------------------------
__global__ __launch_bounds__(256) void k4b_mfma(const unsigned short* __restrict__ pnm,
                                                const unsigned short* __restrict__ protoT_bf,
                                                float* __restrict__ out) {
    const int b = blockIdx.y;
    const int wv = threadIdx.x >> 6, lane = threadIdx.x & 63;
    const int li = lane & 15, lk = lane >> 4;
    const int n0 = blockIdx.x * 64;
    const int cb = wv * 64;
    const f32x4 zv = {0.f, 0.f, 0.f, 0.f};
    f32x4 acc[4][4];
#pragma unroll
    for (int s = 0; s < 4; ++s)
#pragma unroll
        for (int u = 0; u < 4; ++u) acc[s][u] = zv;
    const unsigned short* ar = pnm + ((size_t)b * N + n0 + li) * M + lk * 8;
    const unsigned short* br = protoT_bf + ((size_t)b * C + cb + li) * M + lk * 8;
#pragma unroll
    for (int m0 = 0; m0 < M; m0 += 32) {
        s16x8 af[4], bf_[4];
#pragma unroll
        for (int s = 0; s < 4; ++s) af[s] = *(const s16x8*)(ar + (size_t)(s * 16) * M + m0);
#pragma unroll
        for (int u = 0; u < 4; ++u) bf_[u] = *(const s16x8*)(br + (size_t)(u * 16) * M + m0);
#pragma unroll
        for (int s = 0; s < 4; ++s)
#pragma unroll
            for (int u = 0; u < 4; ++u) acc[s][u] = MFMA(af[s], bf_[u], acc[s][u]);
    }
    __shared__ float ls[4][64];
    __shared__ float ls2[64];
    float psq[4][4];
#pragma unroll
    for (int s = 0; s < 4; ++s)
#pragma unroll
        for (int r = 0; r < 4; ++r) {
            float sum = 0.f;
#pragma unroll
            for (int u = 0; u < 4; ++u) sum += acc[s][u][r] * acc[s][u][r];
#pragma unroll
            for (int off = 8; off >= 1; off >>= 1) sum += __shfl_xor(sum, off);
            psq[s][r] = sum;
        }
    if (li == 0) {
#pragma unroll
        for (int s = 0; s < 4; ++s)
#pragma unroll
            for (int r = 0; r < 4; ++r) ls[wv][s * 16 + lk * 4 + r] = psq[s][r];
    }
    __syncthreads();
    if (threadIdx.x < 64) {
        const int tt = threadIdx.x;
        const float tot = ls[0][tt] + ls[1][tt] + ls[2][tt] + ls[3][tt];
        ls2[tt] = 1.f / fmaxf(sqrtf(tot), EPS);
    }
    __syncthreads();
    float scl[4][4];
#pragma unroll
    for (int s = 0; s < 4; ++s)
#pragma unroll
        for (int r = 0; r < 4; ++r) scl[s][r] = ls2[s * 16 + lk * 4 + r];
    float* ob = out + (size_t)b * C * N;
#pragma unroll
    for (int s = 0; s < 4; ++s)
#pragma unroll
        for (int u = 0; u < 4; ++u) {
            f32x4 q;
#pragma unroll
            for (int r = 0; r < 4; ++r) q[r] = acc[s][u][r] * scl[s][r];
            *(f32x4*)(ob + (size_t)(cb + u * 16 + li) * N + n0 + s * 16 + lk * 4) = q;
        }
}

// ---------------------------------------------------------------------------
// K5 / K6: losses.
// ---------------------------------------------------------------------------
__global__ __launch_bounds__(256) void k5_dis(const unsigned short* __restrict__ proto_bf,
                                              const float* __restrict__ p2,
                                              float* __restrict__ dparts) {
    const int q = blockIdx.x;
    const int b = blockIdx.y;
    const unsigned short* pr = proto_bf + (size_t)b * M * C;
    __shared__ float pl[M * C];
    for (int idx = threadIdx.x; idx < M * C; idx += 256) {
        int m = idx >> 8, c = idx & 255;
        pl[m * 256 + (c ^ (m & 31))] = bf2f(pr[idx]);
    }
    __syncthreads();
    float sum = 0.f;
    for (int k = 0; k < 2; ++k) {
        const int pair = q * 512 + k * 256 + threadIdx.x;
        const int i = pair >> 6, j = pair & 63;
        if (j > i) {
            float g = 0.f;
#pragma unroll 8
            for (int c = 0; c < C; ++c)
                g += pl[i * 256 + (c ^ (i & 31))] * pl[j * 256 + (c ^ (j & 31))];
            const float d = 1.f - (p2[b * M + i] + p2[b * M + j] - 2.f * g);
            sum += fmaxf(d, 0.f);
        }
    }
#pragma unroll
    for (int off = 32; off >= 1; off >>= 1) sum += __shfl_xor(sum, off);
    __shared__ float red[4];
    const int wave = threadIdx.x >> 6, lane = threadIdx.x & 63;
    if (lane == 0) red[wave] = sum;
    __syncthreads();
    if (threadIdx.x == 0) dparts[b * 8 + q] = red[0] + red[1] + red[2] + red[3];
}

__global__ __launch_bounds__(256) void k6_final(const float* __restrict__ cparts, int ncp,
                                                const float* __restrict__ dparts,
                                                float* __restrict__ losses) {
    const int t = threadIdx.x;
    float cs = 0.f;
    for (int i = t; i < ncp; i += 256) cs += cparts[i];
    float ds = dparts[t];
#pragma unroll
    for (int off = 32; off >= 1; off >>= 1) {
        cs += __shfl_xor(cs, off);
        ds += __shfl_xor(ds, off);
    }
    __shared__ float rc[4], rd[4];
    const int wave = t >> 6, lane = t & 63;
    if (lane == 0) { rc[wave] = cs; rd[wave] = ds; }
    __syncthreads();
    if (t == 0) {
        const float ctot = rc[0] + rc[1] + rc[2] + rc[3];
        const float dtot = rd[0] + rd[1] + rd[2] + rd[3];
        losses[0] = ctot / ((float)B * (float)N * (float)C);
        losses[1] = dtot * (2.f / (float)(M * (M - 1))) / (float)B;
    }
}

extern "C" void kernel_launch(void* const* d_in, const int* in_sizes, int n_in,
                              void* d_out, int out_size, void* d_ws, size_t ws_size,
                              hipStream_t stream) {
    const float* x = (const float*)d_in[0];
    const float* Wf = (const float*)d_in[1];
    float* out = (float*)d_out;
    float* wsf = (float*)d_ws;
    float* losses = out + (size_t)B * C * N;

    // Proven layout (r3/r4): xbt in d_out (dead before k4b overwrites), rest in ws.
    // ws (floats): Sbf/parts [0, 4,194,304) | Pbf/pnm [4,194,304, 8,388,608)
    //   | xsq [8,388,608, 8,519,680) | proto_bf [8,519,680, 8,781,824)
    //   | protoT_bf [8,781,824, 9,043,968) | p2 @9,052,160 | cparts @9,054,208
    //   | dparts @9,054,720   -- total 36.2 MB
    unsigned short* xbt = (unsigned short*)d_out;
    unsigned short* Sbf = (unsigned short*)wsf;
    float* parts = wsf;
    unsigned short* Pbf = (unsigned short*)(wsf + 4194304);
    unsigned short* pnm = Pbf;
    float* xsq = wsf + 8388608;
    unsigned short* proto_bf = (unsigned short*)(wsf + 8519680);
    unsigned short* protoT_bf = (unsigned short*)(wsf + 8781824);
    float* p2 = wsf + 9052160;
    float* cparts = wsf + 9054208;
    float* dparts = wsf + 9054720;

    k01<<<dim3(N / 64, B), 256, 0, stream>>>(x, Wf, xbt, Sbf, xsq);
    k2_softmax_n<<<dim3(M, B), 256, 0, stream>>>(Sbf, Pbf);
    k3_mfma<<<dim3(8, B), 256, 0, stream>>>(x, Pbf, parts);
    k3b_reduce<<<dim3(8, B), 256, 0, stream>>>(parts, proto_bf, protoT_bf, p2);
    k4_score<<<dim3(N / 256, B), 256, 0, stream>>>(proto_bf, xbt, p2, xsq, pnm, cparts);
    k4b_mfma<<<dim3(N / 64, B), 256, 0, stream>>>(pnm, protoT_bf, out);
    k5_dis<<<dim3(8, B), 256, 0, stream>>>(proto_bf, p2, dparts);
    k6_final<<<1, 256, 0, stream>>>(cparts, B * 16, dparts, losses);
}